// Round 4
// baseline (916.887 us; speedup 1.0000x reference)
//
#include <hip/hip_runtime.h>
#include <math.h>

#define NNODES 50000
#define NEDGES 800000
#define FIN    1433
#define KP1    1440   // FIN padded to multiple of 32
#define HDIM   256
#define NCLS   7
#define MPAD   50048  // NNODES padded to multiple of 128

typedef __attribute__((ext_vector_type(8))) short short8;
typedef __attribute__((ext_vector_type(4))) float f32x4;

__device__ __forceinline__ unsigned short f2bf(float f) {
    unsigned u = __builtin_bit_cast(unsigned, f);
    u += 0x7fffu + ((u >> 16) & 1u);          // round-to-nearest-even
    return (unsigned short)(u >> 16);
}

__device__ __forceinline__ float bf2f(unsigned short u) {
    unsigned v = ((unsigned)u) << 16;
    return __builtin_bit_cast(float, v);
}

__device__ __forceinline__ void gl2lds16(const void* g, void* l) {
    __builtin_amdgcn_global_load_lds(
        (const __attribute__((address_space(1))) unsigned int*)g,
        (__attribute__((address_space(3))) unsigned int*)l, 16, 0, 0);
}

// ---------------- CSR construction ----------------

__global__ void count_kernel(const int* __restrict__ col, int* __restrict__ cnt, int E) {
    int e = blockIdx.x * blockDim.x + threadIdx.x;
    if (e < E) atomicAdd(&cnt[col[e]], 1);
}

// scan + dinv fused: dinv = rsqrt(deg+1) computed from the same cnt pass
__global__ __launch_bounds__(1024) void scan_kernel(const int* __restrict__ cnt,
                                                    int* __restrict__ rp,
                                                    float* __restrict__ dinv,
                                                    int n, int total) {
    __shared__ int sums[1024];
    int t = threadIdx.x;
    int chunk = (n + 1023) >> 10;
    int start = t * chunk;
    int end = start + chunk; if (end > n) end = n;
    int local = 0;
    for (int j = start; j < end; ++j) local += cnt[j];
    sums[t] = local;
    __syncthreads();
    for (int off = 1; off < 1024; off <<= 1) {
        int v = (t >= off) ? sums[t - off] : 0;
        __syncthreads();
        sums[t] += v;
        __syncthreads();
    }
    int run = (t == 0) ? 0 : sums[t - 1];
    for (int j = start; j < end; ++j) {
        int c = cnt[j];
        rp[j] = run; run += c;
        dinv[j] = rsqrtf((float)(c + 1));
    }
    if (t == 0) rp[n] = total;
}

__global__ void fill_kernel(const int* __restrict__ row, const int* __restrict__ col,
                            const int* __restrict__ rp, int* __restrict__ cur,
                            int* __restrict__ csr, int E) {
    int e = blockIdx.x * blockDim.x + threadIdx.x;
    if (e < E) {
        int c = col[e];
        int pos = rp[c] + atomicAdd(&cur[c], 1);
        csr[pos] = row[e];
    }
}

// ---------------- weight transpose+cast: Wt[Nn][Kp] <- W[Kin][Nn] ----------------

__global__ void cast_wt_kernel(const float* __restrict__ W, unsigned short* __restrict__ Wt,
                               int Kin, int Kp, int Nn) {
    int idx = blockIdx.x * blockDim.x + threadIdx.x;
    if (idx >= Nn * Kp) return;
    int n = idx / Kp, k = idx % Kp;
    float f = (k < Kin) ? W[(size_t)k * Nn + n] : 0.f;
    Wt[idx] = f2bf(f);
}

// ---------------- layer-1 GEMM, fused f32->bf16 A staging ----------------
// C[M,256] bf16 = X[M,FIN] f32 @ Bt[256,KP1]^T bf16. BM=64, BN=256, BK=32, 256 thr = 4 waves.
// LDS chunk layout (16B chunks): chunk(m,kq) stored at m*4 + (kq ^ ((m>>1)&3)).
// B staged via global_load_lds width-16; A loaded as guarded scalar f32 (rows are 4B-aligned
// only: FIN*4=5732 B row stride), converted in regs, ds_write_b128 into the same layout.

__global__ __launch_bounds__(256) void gemm_f32a(const float* __restrict__ X,
                                                 const unsigned short* __restrict__ Bt,
                                                 unsigned short* __restrict__ C) {
    __shared__ __align__(16) unsigned short As[64 * 32];     // 4 KB
    __shared__ __align__(16) unsigned short Bs[256 * 32];    // 16 KB
    const int tid = threadIdx.x;
    const int wave = tid >> 6, lane = tid & 63;
    const int m0 = blockIdx.x * 64;
    const int wn = wave * 64;

    // B staging: 1024 chunks, 4 per thread (wave-uniform base + lane*16)
    const unsigned short* pB[4];
    unsigned short* ldsB[4];
    #pragma unroll
    for (int i = 0; i < 4; ++i) {
        int c = i * 256 + wave * 64 + lane;
        int nB = c >> 2, kqB = (c & 3) ^ ((nB >> 1) & 3);
        pB[i] = Bt + (size_t)nB * KP1 + kqB * 8;
        ldsB[i] = &Bs[c * 8];
    }
    // A staging: thread -> (row ra, col-group ca of 8 f32)
    const int ra = tid >> 2, ca = tid & 3;
    const bool rowok = (m0 + ra) < NNODES;
    const float* xp = X + (size_t)(m0 + ra) * FIN + ca * 8;
    unsigned short* ldsA = &As[(ra * 4 + (ca ^ ((ra >> 1) & 3))) * 8];

    // fragment read offsets (A shared by all 4 waves; B per-wave column strip)
    int aoff[4], boff[4];
    const int kq = lane >> 4;
    #pragma unroll
    for (int i = 0; i < 4; ++i) {
        int ml = i * 16 + (lane & 15);
        aoff[i] = (ml * 4 + (kq ^ ((ml >> 1) & 3))) * 8;
        int nl = wn + i * 16 + (lane & 15);
        boff[i] = (nl * 4 + (kq ^ ((nl >> 1) & 3))) * 8;
    }

    f32x4 acc[4][4] = {};

    for (int k0 = 0; k0 < KP1; k0 += 32) {
        int kbase = k0 + ca * 8;
        float f[8];
        if (rowok && kbase + 8 <= FIN) {
            #pragma unroll
            for (int j = 0; j < 8; ++j) f[j] = xp[j];
        } else {
            #pragma unroll
            for (int j = 0; j < 8; ++j)
                f[j] = (rowok && kbase + j < FIN) ? xp[j] : 0.f;
        }
        xp += 32;
        #pragma unroll
        for (int i = 0; i < 4; ++i) { gl2lds16(pB[i], ldsB[i]); pB[i] += 32; }
        short8 v;
        #pragma unroll
        for (int j = 0; j < 8; ++j) v[j] = (short)f2bf(f[j]);
        *(short8*)ldsA = v;
        __syncthreads();
        short8 af[4], bfr[4];
        #pragma unroll
        for (int i = 0; i < 4; ++i) af[i]  = *(const short8*)&As[aoff[i]];
        #pragma unroll
        for (int j = 0; j < 4; ++j) bfr[j] = *(const short8*)&Bs[boff[j]];
        #pragma unroll
        for (int i = 0; i < 4; ++i)
            #pragma unroll
            for (int j = 0; j < 4; ++j)
                acc[i][j] = __builtin_amdgcn_mfma_f32_16x16x32_bf16(af[i], bfr[j], acc[i][j], 0, 0, 0);
        __syncthreads();
    }

    // C/D layout: col = lane&15, row = (lane>>4)*4 + reg
    #pragma unroll
    for (int i = 0; i < 4; ++i) {
        int gm_base = m0 + i * 16 + (lane >> 4) * 4;
        #pragma unroll
        for (int r = 0; r < 4; ++r) {
            int gm = gm_base + r;
            if (gm < NNODES) {
                #pragma unroll
                for (int j = 0; j < 4; ++j) {
                    int gn = wn + j * 16 + (lane & 15);
                    C[(size_t)gm * HDIM + gn] = f2bf(acc[i][j][r]);
                }
            }
        }
    }
}

// ---------------- bf16 MFMA GEMM (layer 2): C bf16 = A bf16 @ Bt^T bf16 ----------------
// 128x128 tile, BK=32, 256 threads = 4 waves, each wave 64x64.

__global__ __launch_bounds__(256) void gemm_bf16(const unsigned short* __restrict__ A,
                                                 const unsigned short* __restrict__ Bt,
                                                 unsigned short* __restrict__ C,
                                                 int M, int K, int Nn) {
    __shared__ __align__(16) unsigned short As[128 * 32];
    __shared__ __align__(16) unsigned short Bs[128 * 32];
    const int tid = threadIdx.x;
    const int wave = tid >> 6, lane = tid & 63;
    const int m0 = blockIdx.x * 128, n0 = blockIdx.y * 128;
    const int wm = (wave >> 1) * 64, wn = (wave & 1) * 64;

    const int c0 = wave * 64 + lane;
    const int c1 = 256 + wave * 64 + lane;
    int mA0 = c0 >> 2, kqA0 = (c0 & 3) ^ ((mA0 >> 1) & 3);
    int mA1 = c1 >> 2, kqA1 = (c1 & 3) ^ ((mA1 >> 1) & 3);
    const unsigned short* pA0 = A + (size_t)(m0 + mA0) * K + kqA0 * 8;
    const unsigned short* pA1 = A + (size_t)(m0 + mA1) * K + kqA1 * 8;
    const unsigned short* pB0 = Bt + (size_t)(n0 + mA0) * K + kqA0 * 8;
    const unsigned short* pB1 = Bt + (size_t)(n0 + mA1) * K + kqA1 * 8;
    unsigned short* ldsA0 = &As[(wave * 64) * 8];
    unsigned short* ldsA1 = &As[(256 + wave * 64) * 8];
    unsigned short* ldsB0 = &Bs[(wave * 64) * 8];
    unsigned short* ldsB1 = &Bs[(256 + wave * 64) * 8];

    int aoff[4], boff[4];
    const int kq = lane >> 4;
    #pragma unroll
    for (int i = 0; i < 4; ++i) {
        int ml = wm + i * 16 + (lane & 15);
        aoff[i] = (ml * 4 + (kq ^ ((ml >> 1) & 3))) * 8;
        int nl = wn + i * 16 + (lane & 15);
        boff[i] = (nl * 4 + (kq ^ ((nl >> 1) & 3))) * 8;
    }

    f32x4 acc[4][4] = {};

    for (int k0 = 0; k0 < K; k0 += 32) {
        gl2lds16(pA0, ldsA0);
        gl2lds16(pA1, ldsA1);
        gl2lds16(pB0, ldsB0);
        gl2lds16(pB1, ldsB1);
        pA0 += 32; pA1 += 32; pB0 += 32; pB1 += 32;
        __syncthreads();
        short8 af[4], bfr[4];
        #pragma unroll
        for (int i = 0; i < 4; ++i) af[i]  = *(const short8*)&As[aoff[i]];
        #pragma unroll
        for (int j = 0; j < 4; ++j) bfr[j] = *(const short8*)&Bs[boff[j]];
        #pragma unroll
        for (int i = 0; i < 4; ++i)
            #pragma unroll
            for (int j = 0; j < 4; ++j)
                acc[i][j] = __builtin_amdgcn_mfma_f32_16x16x32_bf16(af[i], bfr[j], acc[i][j], 0, 0, 0);
        __syncthreads();
    }

    #pragma unroll
    for (int i = 0; i < 4; ++i) {
        int gm_base = m0 + wm + i * 16 + (lane >> 4) * 4;
        #pragma unroll
        for (int r = 0; r < 4; ++r) {
            int gm = gm_base + r;
            if (gm < M) {
                #pragma unroll
                for (int j = 0; j < 4; ++j) {
                    int gn = n0 + wn + j * 16 + (lane & 15);
                    C[(size_t)gm * Nn + gn] = f2bf(acc[i][j][r]);
                }
            }
        }
    }
}

// ---------------- aggregation layer 1 (bf16 in/out, f32 accumulate) ----------------

__global__ __launch_bounds__(256) void agg_kernel(const ushort4* __restrict__ h,
                                                  ushort4* __restrict__ out,
                                                  const float* __restrict__ dinv,
                                                  const int* __restrict__ rp,
                                                  const int* __restrict__ csr,
                                                  const float* __restrict__ bias,
                                                  int n) {
    int node = blockIdx.x * 4 + (threadIdx.x >> 6);
    int lane = threadIdx.x & 63;
    if (node >= n) return;
    float di = dinv[node];
    float sw = di * di;
    ushort4 hv = h[node * 64 + lane];
    float ax = sw * bf2f(hv.x), ay = sw * bf2f(hv.y);
    float az = sw * bf2f(hv.z), aw = sw * bf2f(hv.w);
    int p0 = rp[node], p1 = rp[node + 1];
    for (int p = p0; p < p1; ++p) {
        int s = csr[p];
        float wgt = dinv[s] * di;
        ushort4 t = h[s * 64 + lane];
        ax += wgt * bf2f(t.x); ay += wgt * bf2f(t.y);
        az += wgt * bf2f(t.z); aw += wgt * bf2f(t.w);
    }
    float4 b = ((const float4*)bias)[lane];
    ax = fmaxf(ax + b.x, 0.f); ay = fmaxf(ay + b.y, 0.f);
    az = fmaxf(az + b.z, 0.f); aw = fmaxf(aw + b.w, 0.f);
    out[node * 64 + lane] = make_ushort4(f2bf(ax), f2bf(ay), f2bf(az), f2bf(aw));
}

// ---------------- aggregation layer 2 fused with mm3: h3[N,7] ----------------
// Wave aggregates a 256-wide row in regs (4 f32/lane), bias+relu, then dots with W3
// (LDS, transposed to [c][k] so lanes read contiguous float4 -> conflict-free b128),
// shuffle-reduces 7 partials, lane 0 writes.

__global__ __launch_bounds__(256) void agg2_mm3_kernel(const ushort4* __restrict__ h,
                                                       float* __restrict__ h3,
                                                       const float* __restrict__ dinv,
                                                       const int* __restrict__ rp,
                                                       const int* __restrict__ csr,
                                                       const float* __restrict__ bias,
                                                       const float* __restrict__ W3,
                                                       int n) {
    __shared__ __align__(16) float Ws[NCLS * HDIM];   // Ws[c*256 + k] = W3[k*7 + c]
    int tid = threadIdx.x;
    for (int i = tid; i < NCLS * HDIM; i += 256)
        Ws[i] = W3[(i & 255) * NCLS + (i >> 8)];
    __syncthreads();

    int node = blockIdx.x * 4 + (tid >> 6);
    int lane = tid & 63;
    if (node >= n) return;
    float di = dinv[node];
    float sw = di * di;
    ushort4 hv = h[node * 64 + lane];
    float ax = sw * bf2f(hv.x), ay = sw * bf2f(hv.y);
    float az = sw * bf2f(hv.z), aw = sw * bf2f(hv.w);
    int p0 = rp[node], p1 = rp[node + 1];
    for (int p = p0; p < p1; ++p) {
        int s = csr[p];
        float wgt = dinv[s] * di;
        ushort4 t = h[s * 64 + lane];
        ax += wgt * bf2f(t.x); ay += wgt * bf2f(t.y);
        az += wgt * bf2f(t.z); aw += wgt * bf2f(t.w);
    }
    float4 b = ((const float4*)bias)[lane];
    ax = fmaxf(ax + b.x, 0.f); ay = fmaxf(ay + b.y, 0.f);
    az = fmaxf(az + b.z, 0.f); aw = fmaxf(aw + b.w, 0.f);

    float p7[NCLS];
    #pragma unroll
    for (int c = 0; c < NCLS; ++c) {
        float4 w4 = *(const float4*)&Ws[c * HDIM + 4 * lane];
        p7[c] = ax * w4.x + ay * w4.y + az * w4.z + aw * w4.w;
    }
    #pragma unroll
    for (int c = 0; c < NCLS; ++c)
        for (int off = 32; off > 0; off >>= 1) p7[c] += __shfl_down(p7[c], off);
    if (lane == 0) {
        #pragma unroll
        for (int c = 0; c < NCLS; ++c) h3[node * NCLS + c] = p7[c];
    }
}

// ---------------- layer-3 aggregation + bias + log_softmax ----------------

__global__ void final_kernel(const float* __restrict__ h3, const float* __restrict__ dinv,
                             const int* __restrict__ rp, const int* __restrict__ csr,
                             const float* __restrict__ b3, float* __restrict__ out, int n) {
    int i = blockIdx.x * blockDim.x + threadIdx.x;
    if (i >= n) return;
    float di = dinv[i];
    float sw = di * di;
    float acc[NCLS];
    #pragma unroll
    for (int c = 0; c < NCLS; ++c) acc[c] = sw * h3[i * NCLS + c];
    int p0 = rp[i], p1 = rp[i + 1];
    for (int p = p0; p < p1; ++p) {
        int s = csr[p];
        float wgt = dinv[s] * di;
        #pragma unroll
        for (int c = 0; c < NCLS; ++c) acc[c] += wgt * h3[s * NCLS + c];
    }
    float mx = -1e30f;
    #pragma unroll
    for (int c = 0; c < NCLS; ++c) { acc[c] += b3[c]; mx = fmaxf(mx, acc[c]); }
    float sum = 0.f;
    #pragma unroll
    for (int c = 0; c < NCLS; ++c) sum += expf(acc[c] - mx);
    float lse = mx + logf(sum);
    #pragma unroll
    for (int c = 0; c < NCLS; ++c) out[i * NCLS + c] = acc[c] - lse;
}

// ---------------- launch ----------------

extern "C" void kernel_launch(void* const* d_in, const int* in_sizes, int n_in,
                              void* d_out, int out_size, void* d_ws, size_t ws_size,
                              hipStream_t stream) {
    const float* x  = (const float*)d_in[0];
    const int*   ei = (const int*)d_in[1];
    const float* W1 = (const float*)d_in[2];
    const float* b1 = (const float*)d_in[3];
    const float* W2 = (const float*)d_in[4];
    const float* b2 = (const float*)d_in[5];
    const float* W3 = (const float*)d_in[6];
    const float* b3 = (const float*)d_in[7];
    float* out = (float*)d_out;
    const int* row = ei;
    const int* col = ei + NEDGES;

    char* w = (char*)d_ws;
    auto alloc = [&](size_t b) { void* p = (void*)w; w += (b + 255) & ~(size_t)255; return p; };
    int*   cnt  = (int*)alloc(NNODES * 4);
    int*   cur  = (int*)alloc(NNODES * 4);
    int*   rp   = (int*)alloc((NNODES + 1) * 4);
    float* dinv = (float*)alloc(NNODES * 4);
    int*   csr  = (int*)alloc((size_t)NEDGES * 4);
    unsigned short* w1t  = (unsigned short*)alloc((size_t)HDIM * KP1 * 2);
    unsigned short* w2t  = (unsigned short*)alloc((size_t)HDIM * HDIM * 2);
    unsigned short* h_bf = (unsigned short*)alloc((size_t)MPAD * HDIM * 2);
    unsigned short* a_bf = (unsigned short*)alloc((size_t)MPAD * HDIM * 2);
    float* h3 = (float*)alloc((size_t)NNODES * NCLS * 4);
    // pad rows of h_bf/a_bf are never read: CSR indices < NNODES, epilogues guard gm,
    // and pad-row GEMM outputs land in pad rows only. 0xAA poison bf16 is finite.

    hipMemsetAsync(cnt, 0, NNODES * 4, stream);
    hipMemsetAsync(cur, 0, NNODES * 4, stream);
    count_kernel<<<(NEDGES + 255) / 256, 256, 0, stream>>>(col, cnt, NEDGES);
    scan_kernel<<<1, 1024, 0, stream>>>(cnt, rp, dinv, NNODES, NEDGES);
    fill_kernel<<<(NEDGES + 255) / 256, 256, 0, stream>>>(row, col, rp, cur, csr, NEDGES);

    cast_wt_kernel<<<(HDIM * KP1 + 255) / 256, 256, 0, stream>>>(W1, w1t, FIN, KP1, HDIM);
    cast_wt_kernel<<<(HDIM * HDIM + 255) / 256, 256, 0, stream>>>(W2, w2t, HDIM, HDIM, HDIM);

    gemm_f32a<<<MPAD / 64, 256, 0, stream>>>(x, w1t, h_bf);
    agg_kernel<<<(NNODES + 3) / 4, 256, 0, stream>>>((const ushort4*)h_bf, (ushort4*)a_bf,
                                                     dinv, rp, csr, b1, NNODES);
    dim3 g2(MPAD / 128, HDIM / 128);
    gemm_bf16<<<g2, 256, 0, stream>>>(a_bf, w2t, h_bf, NNODES, HDIM, HDIM);
    agg2_mm3_kernel<<<(NNODES + 3) / 4, 256, 0, stream>>>((const ushort4*)h_bf, h3,
                                                          dinv, rp, csr, b2, W3, NNODES);
    final_kernel<<<(NNODES + 255) / 256, 256, 0, stream>>>(h3, dinv, rp, csr, b3, out, NNODES);
}